// Round 20
// baseline (602.754 us; speedup 1.0000x reference)
//
#include <hip/hip_runtime.h>
#include <hip/hip_bf16.h>
#include <math.h>

#define NN 50000
#define FF 256
#define HH 64
#define LL 8
#define EE 1600000
#define CC 40

#define BK 64                       // dst nodes per bucket
#define NB ((NN + BK - 1) / BK)     // 782 buckets
#define PBK 4096                    // edges per partition block
#define NPART ((EE + PBK - 1) / PBK)

using short8 = __attribute__((ext_vector_type(8))) short;
using short4v = __attribute__((ext_vector_type(4))) short;
using f32x4  = __attribute__((ext_vector_type(4))) float;

static __device__ __forceinline__ unsigned short f2b(float f) {
    union { __hip_bfloat16 h; unsigned short u; } cv;
    cv.h = __float2bfloat16(f);
    return cv.u;
}
static __device__ __forceinline__ float b2f(unsigned short u) {
    return __uint_as_float((unsigned)u << 16);
}
static __device__ __forceinline__ float blo(unsigned u) {
    return __uint_as_float(u << 16);
}
static __device__ __forceinline__ float bhi(unsigned u) {
    return __uint_as_float(u & 0xFFFF0000u);
}

// ---------------- bucket-level histogram (LDS-aggregated) ----------------
__global__ void k_bhist(const int* __restrict__ dst, int* __restrict__ bcnt) {
    __shared__ int lh[NB];
    int t = threadIdx.x;
    int e0 = blockIdx.x * PBK;
    int e1 = min(e0 + PBK, EE);
    for (int i = t; i < NB; i += 256) lh[i] = 0;
    __syncthreads();
    for (int e = e0 + t; e < e1; e += 256)
        atomicAdd(&lh[(unsigned)dst[e] >> 6], 1);
    __syncthreads();
    for (int i = t; i < NB; i += 256)
        if (lh[i]) atomicAdd(&bcnt[i], lh[i]);
}

// exclusive scan of NB bucket counts (one 1024-thread block)
__global__ void k_bscan(const int* __restrict__ bcnt, int* __restrict__ bbase) {
    __shared__ int buf[1024];
    int t = threadIdx.x;
    int v = (t < NB) ? bcnt[t] : 0;
    int vin = v;
    buf[t] = v;
    __syncthreads();
    for (int off = 1; off < 1024; off <<= 1) {
        int u = (t >= off) ? buf[t - off] : 0;
        __syncthreads();
        buf[t] += u;
        __syncthreads();
    }
    if (t < NB) bbase[t] = buf[t] - vin;  // exclusive
    if (t == 0) bbase[NB] = EE;
}

__global__ void k_binit(const int* __restrict__ bbase, int* __restrict__ bcur) {
    int t = blockIdx.x * 256 + threadIdx.x;
    if (t < NB) bcur[t] = bbase[t];
}

// ---------------- pass 1: bucket partition (dst>>6), LDS-aggregated runs ----------------
__global__ void k_part(const int* __restrict__ src, const int* __restrict__ dst,
                       const float* __restrict__ w, int* __restrict__ bcur,
                       uint2* __restrict__ ebuk) {
    __shared__ int lh[NB];
    __shared__ int lbase[NB];
    int t = threadIdx.x;
    int e0 = blockIdx.x * PBK;
    int e1 = min(e0 + PBK, EE);
    for (int i = t; i < NB; i += 256) lh[i] = 0;
    __syncthreads();
    for (int e = e0 + t; e < e1; e += 256)
        atomicAdd(&lh[(unsigned)dst[e] >> 6], 1);
    __syncthreads();
    for (int i = t; i < NB; i += 256) {
        int c = lh[i];
        lbase[i] = c ? atomicAdd(&bcur[i], c) : 0;
    }
    __syncthreads();
    for (int i = t; i < NB; i += 256) lh[i] = 0;
    __syncthreads();
    for (int e = e0 + t; e < e1; e += 256) {
        int d = dst[e];
        int b = (unsigned)d >> 6;
        int r = atomicAdd(&lh[b], 1);
        ebuk[lbase[b] + r] = make_uint2(((unsigned)src[e] << 16) | (unsigned)f2b(w[e]),
                                        (unsigned)d);
    }
}

// ---------------- pass 2: per-bucket count + scan + row_ptr + local scatter ----------------
__global__ void k_sub(const int* __restrict__ bbase, const uint2* __restrict__ ebuk,
                      unsigned* __restrict__ pay, int* __restrict__ row_ptr) {
    __shared__ int lcnt[BK];
    __shared__ int lcur[BK];
    int b = blockIdx.x;
    int d0 = b * BK;
    int bksz = min(BK, NN - d0);
    int t = threadIdx.x;
    if (t < BK) lcnt[t] = 0;
    __syncthreads();
    int lo = bbase[b], hi = bbase[b + 1];
    for (int i = lo + t; i < hi; i += 256)
        atomicAdd(&lcnt[ebuk[i].y - d0], 1);
    __syncthreads();
    if (t < 64) {
        int vin = lcnt[t];
        int v = vin;
        for (int off = 1; off < 64; off <<= 1) {
            int u = __shfl_up(v, off);
            if (t >= off) v += u;
        }
        int excl = v - vin + lo;
        lcur[t] = excl;
        if (t < bksz) row_ptr[d0 + t] = excl;
    }
    if (b == NB - 1 && t == 0) row_ptr[NN] = EE;
    __syncthreads();
    for (int i = lo + t; i < hi; i += 256) {
        uint2 pk = ebuk[i];
        int p = atomicAdd(&lcur[pk.y - d0], 1);
        pay[p] = pk.x;
    }
}

// ---------------- W2 -> bf16, layout [ct][i][cr][j] ----------------
__global__ void k_w2b(const float* __restrict__ W2, unsigned short* __restrict__ W2b) {
    int o = blockIdx.x * 256 + threadIdx.x;
    if (o < 3 * 64 * 16 * 64) {
        int j = o & 63;
        int cr = (o >> 6) & 15;
        int i = (o >> 10) & 63;
        int ct = o >> 16;
        int c = ct * 16 + cr;
        float v = (c < CC) ? W2[((size_t)i * 64 + j) * CC + c] : 0.f;
        W2b[o] = f2b(v);
    }
}

// ---------------- initial projection via MFMA: h0 = relu(x @ W0 + b0) ----------------
__global__ __launch_bounds__(512) void k_h0m(const float* __restrict__ x,
                                             const float* __restrict__ W0,
                                             const float* __restrict__ b0,
                                             float* __restrict__ h0f,
                                             unsigned short* __restrict__ h0b) {
    __shared__ __align__(16) __hip_bfloat16 ax[256][72];
    __shared__ __align__(16) __hip_bfloat16 bw[64][72];

    int tid = threadIdx.x;
    int lane = tid & 63;
    int w = tid >> 6;
    int nbase = blockIdx.x * 256;

    f32x4 acc[2][4];
#pragma unroll
    for (int nf = 0; nf < 2; ++nf)
#pragma unroll
        for (int cf = 0; cf < 4; ++cf) acc[nf][cf] = (f32x4){0.f, 0.f, 0.f, 0.f};

    int arow = w * 32 + (lane & 15);
    int kq = (lane >> 4) * 8;

    for (int kc = 0; kc < 4; ++kc) {
        __syncthreads();
#pragma unroll
        for (int p = 0; p < 8; ++p) {
            int q = p * 512 + tid;
            int r = q >> 4, cq = q & 15;
            int node = nbase + r;
            float4 v = {0.f, 0.f, 0.f, 0.f};
            if (node < NN) v = *(const float4*)&x[(size_t)node * FF + kc * 64 + cq * 4];
            __hip_bfloat16* d = &ax[r][cq * 4];
            d[0] = __float2bfloat16(v.x);
            d[1] = __float2bfloat16(v.y);
            d[2] = __float2bfloat16(v.z);
            d[3] = __float2bfloat16(v.w);
        }
#pragma unroll
        for (int u = 0; u < 8; ++u) {
            int k = (tid >> 6) * 8 + u;
            float v = W0[(size_t)(kc * 64 + k) * HH + lane];
            bw[lane][k] = __float2bfloat16(v);
        }
        __syncthreads();
#pragma unroll
        for (int ks = 0; ks < 2; ++ks) {
            short8 a0 = *(const short8*)&ax[arow][ks * 32 + kq];
            short8 a1 = *(const short8*)&ax[arow + 16][ks * 32 + kq];
#pragma unroll
            for (int cf = 0; cf < 4; ++cf) {
                short8 b = *(const short8*)&bw[cf * 16 + (lane & 15)][ks * 32 + kq];
                acc[0][cf] = __builtin_amdgcn_mfma_f32_16x16x32_bf16(a0, b, acc[0][cf], 0, 0, 0);
                acc[1][cf] = __builtin_amdgcn_mfma_f32_16x16x32_bf16(a1, b, acc[1][cf], 0, 0, 0);
            }
        }
    }

#pragma unroll
    for (int nf = 0; nf < 2; ++nf) {
#pragma unroll
        for (int cf = 0; cf < 4; ++cf) {
            int c = cf * 16 + (lane & 15);
            float bias = b0[c];
#pragma unroll
            for (int r = 0; r < 4; ++r) {
                int node = nbase + w * 32 + nf * 16 + ((lane >> 4) << 2) + r;
                if (node < NN) {
                    float v = fmaxf(acc[nf][cf][r] + bias, 0.f);
                    h0f[(size_t)node * HH + c] = v;
                    h0b[(size_t)node * HH + c] = f2b(v);
                }
            }
        }
    }
}

// ---------------- fused layer: dwordx4 gather SpMM + blend + matvec + relu ----------------
// Lane layout: eg = lane&7 (edge slot), cb = lane>>3 (channel block of 8).
// Per 8-edge group each lane does ONE 16B load (8 channels of its edge) —
// 4x fewer VMEM instructions, 4x bytes per outstanding slot. Reduce over edge
// slots via shfl_xor(1/2/4); channel select is lane-local (cndmask tree).
__global__ __launch_bounds__(256, 8) void k_layer(
        const unsigned short* __restrict__ hin, const float* __restrict__ h0,
        const int* __restrict__ row_ptr, const unsigned* __restrict__ pay,
        const float* __restrict__ Wl, float beta,
        unsigned short* __restrict__ hout) {
    int lane = threadIdx.x & 63;
    int eg = lane & 7;
    int cb = lane >> 3;
    int n0 = (blockIdx.x * 4 + (threadIdx.x >> 6)) * 4;

    const uint4* __restrict__ hin4 = (const uint4*)hin;

    float hmix[4];
#pragma unroll
    for (int u = 0; u < 4; ++u) {
        int n = n0 + u;
        int rb = row_ptr[n], re = row_ptr[n + 1];
        float a0 = 0.f, a1 = 0.f, a2 = 0.f, a3 = 0.f;
        float a4 = 0.f, a5 = 0.f, a6 = 0.f, a7 = 0.f;
        for (int base = rb; base < re; base += 64) {
            int idx = base + lane;
            unsigned pv = (idx < re) ? pay[idx] : 0u;  // pad: src=0, w=+0
            int ecnt = min(64, re - base);
            for (int k = 0; k < ecnt; k += 8) {
                unsigned pw = (unsigned)__shfl((int)pv, k + eg);
                float wv = __uint_as_float((pw & 0xFFFFu) << 16);
                uint4 v = hin4[(size_t)(pw >> 16) * 8 + cb];
                a0 = fmaf(wv, blo(v.x), a0);
                a1 = fmaf(wv, bhi(v.x), a1);
                a2 = fmaf(wv, blo(v.y), a2);
                a3 = fmaf(wv, bhi(v.y), a3);
                a4 = fmaf(wv, blo(v.z), a4);
                a5 = fmaf(wv, bhi(v.z), a5);
                a6 = fmaf(wv, blo(v.w), a6);
                a7 = fmaf(wv, bhi(v.w), a7);
            }
        }
        // reduce over the 8 edge slots (lanes differing in low 3 bits)
#define RED(A) A += __shfl_xor(A, 1); A += __shfl_xor(A, 2); A += __shfl_xor(A, 4);
        RED(a0) RED(a1) RED(a2) RED(a3) RED(a4) RED(a5) RED(a6) RED(a7)
#undef RED
        // lane c holds channels cb*8..cb*8+7; pick channel c -> index lane&7
        float t0 = (lane & 1) ? a1 : a0;
        float t1 = (lane & 1) ? a3 : a2;
        float t2 = (lane & 1) ? a5 : a4;
        float t3 = (lane & 1) ? a7 : a6;
        float v0 = (lane & 2) ? t1 : t0;
        float v1 = (lane & 2) ? t3 : t2;
        float accv = (lane & 4) ? v1 : v0;
        hmix[u] = fmaf(0.9f, accv, 0.1f * h0[(size_t)n * HH + lane]);
    }

    int hb[4];
#pragma unroll
    for (int u = 0; u < 4; ++u) hb[u] = __float_as_int(hmix[u]);
    float a2m[4] = {0.f, 0.f, 0.f, 0.f};
#pragma unroll
    for (int jj = 0; jj < HH; jj++) {
        float wr = Wl[jj * HH + lane];
#pragma unroll
        for (int u = 0; u < 4; ++u) {
            float hj = __int_as_float(__builtin_amdgcn_readlane(hb[u], jj));
            a2m[u] = fmaf(hj, wr, a2m[u]);
        }
    }
#pragma unroll
    for (int u = 0; u < 4; ++u) {
        float outv = (1.f - beta) * hmix[u] + beta * a2m[u];
        hout[(size_t)(n0 + u) * HH + lane] = f2b(fmaxf(outv, 0.f));
    }
}

// ---------------- head via MFMA: coarse LDS staging of W2b, 4 barriers total ----------------
__global__ __launch_bounds__(512) void k_head(const unsigned short* __restrict__ h,
                                              const unsigned short* __restrict__ W2b,
                                              const float* __restrict__ b2,
                                              float* __restrict__ out) {
    __shared__ __align__(16) unsigned short Bl[32 * 1056];  // [i][cr*66 + j]

    int tid = threadIdx.x;
    int lane = tid & 63;
    int w = tid >> 6;
    int nbase = blockIdx.x * 256;
    int ct = blockIdx.y;         // 0..2
    int c0 = ct * 16;

    int kq = (lane >> 4) * 8;
    int arow = w * 32 + (lane & 15);
    int rb4 = w * 32 + ((lane >> 4) << 2);

    int ra0 = min(nbase + arow, NN - 1);
    int ra1 = min(nbase + arow + 16, NN - 1);
    short8 af00 = *(const short8*)&h[(size_t)ra0 * HH + kq];
    short8 af01 = *(const short8*)&h[(size_t)ra0 * HH + 32 + kq];
    short8 af10 = *(const short8*)&h[(size_t)ra1 * HH + kq];
    short8 af11 = *(const short8*)&h[(size_t)ra1 * HH + 32 + kq];

    const unsigned short* srow[8];
#pragma unroll
    for (int r = 0; r < 4; ++r) {
        srow[r]     = &h[(size_t)min(nbase + rb4 + r, NN - 1) * HH];
        srow[4 + r] = &h[(size_t)min(nbase + rb4 + 16 + r, NN - 1) * HH];
    }

    const f32x4 zf = (f32x4){0.f, 0.f, 0.f, 0.f};
    f32x4 acc0 = zf, acc1 = zf;

    const unsigned short* __restrict__ Wslice = W2b + (size_t)ct * 65536;

    for (int ph = 0; ph < 2; ++ph) {
        __syncthreads();
        const unsigned short* src = Wslice + (size_t)ph * 32768;
#pragma unroll
        for (int rnd = 0; rnd < 8; ++rnd) {
            int cid = rnd * 512 + tid;
            int il = cid >> 7;
            int rem = cid & 127;
            int cr = rem >> 3;
            int jg = rem & 7;
            *(short8*)&Bl[il * 1056 + cr * 66 + jg * 8] =
                *(const short8*)&src[(size_t)cid * 8];
        }
        __syncthreads();

#pragma unroll
        for (int ihl = 0; ihl < 8; ++ihl) {
            int ibase = ihl * 4;
            int ig = ph * 32 + ibase;
            short8 B00 = *(const short8*)&Bl[(ibase + 0) * 1056 + (lane & 15) * 66 + kq];
            short8 B01 = *(const short8*)&Bl[(ibase + 0) * 1056 + (lane & 15) * 66 + 32 + kq];
            short8 B10 = *(const short8*)&Bl[(ibase + 1) * 1056 + (lane & 15) * 66 + kq];
            short8 B11 = *(const short8*)&Bl[(ibase + 1) * 1056 + (lane & 15) * 66 + 32 + kq];
            short8 B20 = *(const short8*)&Bl[(ibase + 2) * 1056 + (lane & 15) * 66 + kq];
            short8 B21 = *(const short8*)&Bl[(ibase + 2) * 1056 + (lane & 15) * 66 + 32 + kq];
            short8 B30 = *(const short8*)&Bl[(ibase + 3) * 1056 + (lane & 15) * 66 + kq];
            short8 B31 = *(const short8*)&Bl[(ibase + 3) * 1056 + (lane & 15) * 66 + 32 + kq];
            short4v sa0 = *(const short4v*)&srow[0][ig];
            short4v sa1 = *(const short4v*)&srow[1][ig];
            short4v sa2 = *(const short4v*)&srow[2][ig];
            short4v sa3 = *(const short4v*)&srow[3][ig];
            short4v sb0 = *(const short4v*)&srow[4][ig];
            short4v sb1 = *(const short4v*)&srow[5][ig];
            short4v sb2 = *(const short4v*)&srow[6][ig];
            short4v sb3 = *(const short4v*)&srow[7][ig];

#define ILB(IL, B0, B1)                                                          \
            {                                                                    \
                f32x4 t;                                                         \
                t = __builtin_amdgcn_mfma_f32_16x16x32_bf16(af00, B0, zf, 0, 0, 0); \
                t = __builtin_amdgcn_mfma_f32_16x16x32_bf16(af01, B1, t, 0, 0, 0);  \
                acc0[0] = fmaf(b2f((unsigned short)sa0[IL]), t[0], acc0[0]);     \
                acc0[1] = fmaf(b2f((unsigned short)sa1[IL]), t[1], acc0[1]);     \
                acc0[2] = fmaf(b2f((unsigned short)sa2[IL]), t[2], acc0[2]);     \
                acc0[3] = fmaf(b2f((unsigned short)sa3[IL]), t[3], acc0[3]);     \
                t = __builtin_amdgcn_mfma_f32_16x16x32_bf16(af10, B0, zf, 0, 0, 0); \
                t = __builtin_amdgcn_mfma_f32_16x16x32_bf16(af11, B1, t, 0, 0, 0);  \
                acc1[0] = fmaf(b2f((unsigned short)sb0[IL]), t[0], acc1[0]);     \
                acc1[1] = fmaf(b2f((unsigned short)sb1[IL]), t[1], acc1[1]);     \
                acc1[2] = fmaf(b2f((unsigned short)sb2[IL]), t[2], acc1[2]);     \
                acc1[3] = fmaf(b2f((unsigned short)sb3[IL]), t[3], acc1[3]);     \
            }
            ILB(0, B00, B01)
            ILB(1, B10, B11)
            ILB(2, B20, B21)
            ILB(3, B30, B31)
#undef ILB
        }
    }

    int c = c0 + (lane & 15);
    if (c < CC) {
        float bias = b2[c];
#pragma unroll
        for (int r = 0; r < 4; ++r) {
            int node0 = nbase + rb4 + r;
            if (node0 < NN) out[(size_t)node0 * CC + c] = acc0[r] + bias;
            int node1 = nbase + rb4 + 16 + r;
            if (node1 < NN) out[(size_t)node1 * CC + c] = acc1[r] + bias;
        }
    }
}

// ---------------- log_softmax in place, wave per node ----------------
__global__ void k_lsm(float* __restrict__ out) {
    int lane = threadIdx.x & 63;
    int n = (blockIdx.x * 256 + threadIdx.x) >> 6;
    if (n >= NN) return;
    float x = (lane < CC) ? out[(size_t)n * CC + lane] : -INFINITY;
    float m = x;
    for (int off = 32; off; off >>= 1) m = fmaxf(m, __shfl_xor(m, off));
    float e = (lane < CC) ? expf(x - m) : 0.f;
    float s = e;
    for (int off = 32; off; off >>= 1) s += __shfl_xor(s, off);
    float lse = m + logf(s);
    if (lane < CC) out[(size_t)n * CC + lane] = x - lse;
}

extern "C" void kernel_launch(void* const* d_in, const int* in_sizes, int n_in,
                              void* d_out, int out_size, void* d_ws, size_t ws_size,
                              hipStream_t stream) {
    const float* x  = (const float*)d_in[0];
    const int*   ei = (const int*)d_in[1];
    const float* ew = (const float*)d_in[2];
    const float* W0 = (const float*)d_in[3];
    const float* b0 = (const float*)d_in[4];
    const float* Wl = (const float*)d_in[5];
    const float* W2 = (const float*)d_in[6];
    const float* b2 = (const float*)d_in[7];
    float* out = (float*)d_out;

    char* ws = (char*)d_ws;
    size_t off = 0;
    auto alloc = [&](size_t b) { size_t o = off; off += (b + 255) & ~(size_t)255; return o; };
    float*          h0f = (float*)(ws + alloc((size_t)NN * HH * 4));
    unsigned short* h0b = (unsigned short*)(ws + alloc((size_t)NN * HH * 2));
    unsigned short* hA  = (unsigned short*)(ws + alloc((size_t)NN * HH * 2));
    unsigned short* hB  = (unsigned short*)(ws + alloc((size_t)NN * HH * 2));
    int*      bcnt    = (int*)(ws + alloc((size_t)NB * 4));
    int*      bbase   = (int*)(ws + alloc((size_t)(NB + 1) * 4));
    int*      bcur    = (int*)(ws + alloc((size_t)NB * 4));
    int*      row_ptr = (int*)(ws + alloc((size_t)(NN + 1) * 4));
    uint2*    ebuk    = (uint2*)(ws + alloc((size_t)EE * 8));
    unsigned* pay     = (unsigned*)(ws + alloc((size_t)EE * 4));
    unsigned short* W2b = (unsigned short*)(ws + alloc((size_t)3 * 64 * 16 * 64 * 2));

    const int* srcp = ei;
    const int* dstp = ei + EE;

    hipMemsetAsync(bcnt, 0, (size_t)NB * 4, stream);
    k_bhist<<<NPART, 256, 0, stream>>>(dstp, bcnt);
    k_bscan<<<1, 1024, 0, stream>>>(bcnt, bbase);
    k_binit<<<(NB + 255) / 256, 256, 0, stream>>>(bbase, bcur);
    k_part<<<NPART, 256, 0, stream>>>(srcp, dstp, ew, bcur, ebuk);
    k_sub<<<NB, 256, 0, stream>>>(bbase, ebuk, pay, row_ptr);
    k_w2b<<<768, 256, 0, stream>>>(W2, W2b);

    k_h0m<<<196, 512, 0, stream>>>(x, W0, b0, h0f, h0b);

    const unsigned short* hin = h0b;
    unsigned short* ho = hA;
    for (int l = 0; l < LL; l++) {
        float beta = (float)log(0.5 / (double)(l + 1) + 1.0);
        k_layer<<<3125, 256, 0, stream>>>(hin, h0f, row_ptr, pay,
                                          Wl + (size_t)l * HH * HH, beta, ho);
        hin = ho;
        ho = (ho == hA) ? hB : hA;
    }

    k_head<<<dim3(196, 3), 512, 0, stream>>>(hin, W2b, b2, out);
    k_lsm<<<(NN * 64 + 255) / 256, 256, 0, stream>>>(out);
}

// Round 21
// 556.763 us; speedup vs baseline: 1.0826x; 1.0826x over previous
//
#include <hip/hip_runtime.h>
#include <hip/hip_bf16.h>
#include <math.h>

#define NN 50000
#define FF 256
#define HH 64
#define LL 8
#define EE 1600000
#define CC 40
#define CHS 25000                   // src chunk boundary

#define BK 64                       // dst nodes per bucket
#define NB ((NN + BK - 1) / BK)     // 782 buckets
#define PBK 4096                    // edges per partition block
#define NPART ((EE + PBK - 1) / PBK)

using short8 = __attribute__((ext_vector_type(8))) short;
using short4v = __attribute__((ext_vector_type(4))) short;
using f32x4  = __attribute__((ext_vector_type(4))) float;

static __device__ __forceinline__ unsigned short f2b(float f) {
    union { __hip_bfloat16 h; unsigned short u; } cv;
    cv.h = __float2bfloat16(f);
    return cv.u;
}
static __device__ __forceinline__ float b2f(unsigned short u) {
    return __uint_as_float((unsigned)u << 16);
}

// ---------------- bucket-level histogram (LDS-aggregated) ----------------
__global__ void k_bhist(const int* __restrict__ dst, int* __restrict__ bcnt) {
    __shared__ int lh[NB];
    int t = threadIdx.x;
    int e0 = blockIdx.x * PBK;
    int e1 = min(e0 + PBK, EE);
    for (int i = t; i < NB; i += 256) lh[i] = 0;
    __syncthreads();
    for (int e = e0 + t; e < e1; e += 256)
        atomicAdd(&lh[(unsigned)dst[e] >> 6], 1);
    __syncthreads();
    for (int i = t; i < NB; i += 256)
        if (lh[i]) atomicAdd(&bcnt[i], lh[i]);
}

__global__ void k_bscan(const int* __restrict__ bcnt, int* __restrict__ bbase) {
    __shared__ int buf[1024];
    int t = threadIdx.x;
    int v = (t < NB) ? bcnt[t] : 0;
    int vin = v;
    buf[t] = v;
    __syncthreads();
    for (int off = 1; off < 1024; off <<= 1) {
        int u = (t >= off) ? buf[t - off] : 0;
        __syncthreads();
        buf[t] += u;
        __syncthreads();
    }
    if (t < NB) bbase[t] = buf[t] - vin;  // exclusive
    if (t == 0) bbase[NB] = EE;
}

__global__ void k_binit(const int* __restrict__ bbase, int* __restrict__ bcur) {
    int t = blockIdx.x * 256 + threadIdx.x;
    if (t < NB) bcur[t] = bbase[t];
}

// ---------------- pass 1: bucket partition (dst>>6), LDS-aggregated runs ----------------
__global__ void k_part(const int* __restrict__ src, const int* __restrict__ dst,
                       const float* __restrict__ w, int* __restrict__ bcur,
                       uint2* __restrict__ ebuk) {
    __shared__ int lh[NB];
    __shared__ int lbase[NB];
    int t = threadIdx.x;
    int e0 = blockIdx.x * PBK;
    int e1 = min(e0 + PBK, EE);
    for (int i = t; i < NB; i += 256) lh[i] = 0;
    __syncthreads();
    for (int e = e0 + t; e < e1; e += 256)
        atomicAdd(&lh[(unsigned)dst[e] >> 6], 1);
    __syncthreads();
    for (int i = t; i < NB; i += 256) {
        int c = lh[i];
        lbase[i] = c ? atomicAdd(&bcur[i], c) : 0;
    }
    __syncthreads();
    for (int i = t; i < NB; i += 256) lh[i] = 0;
    __syncthreads();
    for (int e = e0 + t; e < e1; e += 256) {
        int d = dst[e];
        int b = (unsigned)d >> 6;
        int r = atomicAdd(&lh[b], 1);
        ebuk[lbase[b] + r] = make_uint2(((unsigned)src[e] << 16) | (unsigned)f2b(w[e]),
                                        (unsigned)d);
    }
}

// ---------------- pass 2: per-bucket count + scan + row_ptr/row_mid + chunked scatter ----------------
__global__ void k_sub(const int* __restrict__ bbase, const uint2* __restrict__ ebuk,
                      unsigned* __restrict__ pay, int* __restrict__ row_ptr,
                      int* __restrict__ row_mid) {
    __shared__ int lcnt[BK];
    __shared__ int lcnt0[BK];
    __shared__ int lcur0[BK];
    __shared__ int lcur1[BK];
    int b = blockIdx.x;
    int d0 = b * BK;
    int bksz = min(BK, NN - d0);
    int t = threadIdx.x;
    if (t < BK) { lcnt[t] = 0; lcnt0[t] = 0; }
    __syncthreads();
    int lo = bbase[b], hi = bbase[b + 1];
    for (int i = lo + t; i < hi; i += 256) {
        uint2 pk = ebuk[i];
        int dl = pk.y - d0;
        atomicAdd(&lcnt[dl], 1);
        if ((pk.x >> 16) < CHS) atomicAdd(&lcnt0[dl], 1);
    }
    __syncthreads();
    if (t < 64) {
        int vin = lcnt[t];
        int v = vin;
        for (int off = 1; off < 64; off <<= 1) {
            int u = __shfl_up(v, off);
            if (t >= off) v += u;
        }
        int start = v - vin + lo;
        lcur0[t] = start;
        lcur1[t] = start + lcnt0[t];
        if (t < bksz) {
            row_ptr[d0 + t] = start;
            row_mid[d0 + t] = start + lcnt0[t];
        }
    }
    if (b == NB - 1 && t == 0) row_ptr[NN] = EE;
    __syncthreads();
    for (int i = lo + t; i < hi; i += 256) {
        uint2 pk = ebuk[i];
        int dl = pk.y - d0;
        int p = ((pk.x >> 16) < CHS) ? atomicAdd(&lcur0[dl], 1)
                                     : atomicAdd(&lcur1[dl], 1);
        pay[p] = pk.x;
    }
}

// ---------------- W2 -> bf16, layout [ct][i][cr][j] ----------------
__global__ void k_w2b(const float* __restrict__ W2, unsigned short* __restrict__ W2b) {
    int o = blockIdx.x * 256 + threadIdx.x;
    if (o < 3 * 64 * 16 * 64) {
        int j = o & 63;
        int cr = (o >> 6) & 15;
        int i = (o >> 10) & 63;
        int ct = o >> 16;
        int c = ct * 16 + cr;
        float v = (c < CC) ? W2[((size_t)i * 64 + j) * CC + c] : 0.f;
        W2b[o] = f2b(v);
    }
}

// ---------------- initial projection via MFMA: h0 = relu(x @ W0 + b0) ----------------
__global__ __launch_bounds__(512) void k_h0m(const float* __restrict__ x,
                                             const float* __restrict__ W0,
                                             const float* __restrict__ b0,
                                             float* __restrict__ h0f,
                                             unsigned short* __restrict__ h0b) {
    __shared__ __align__(16) __hip_bfloat16 ax[256][72];
    __shared__ __align__(16) __hip_bfloat16 bw[64][72];

    int tid = threadIdx.x;
    int lane = tid & 63;
    int w = tid >> 6;
    int nbase = blockIdx.x * 256;

    f32x4 acc[2][4];
#pragma unroll
    for (int nf = 0; nf < 2; ++nf)
#pragma unroll
        for (int cf = 0; cf < 4; ++cf) acc[nf][cf] = (f32x4){0.f, 0.f, 0.f, 0.f};

    int arow = w * 32 + (lane & 15);
    int kq = (lane >> 4) * 8;

    for (int kc = 0; kc < 4; ++kc) {
        __syncthreads();
#pragma unroll
        for (int p = 0; p < 8; ++p) {
            int q = p * 512 + tid;
            int r = q >> 4, cq = q & 15;
            int node = nbase + r;
            float4 v = {0.f, 0.f, 0.f, 0.f};
            if (node < NN) v = *(const float4*)&x[(size_t)node * FF + kc * 64 + cq * 4];
            __hip_bfloat16* d = &ax[r][cq * 4];
            d[0] = __float2bfloat16(v.x);
            d[1] = __float2bfloat16(v.y);
            d[2] = __float2bfloat16(v.z);
            d[3] = __float2bfloat16(v.w);
        }
#pragma unroll
        for (int u = 0; u < 8; ++u) {
            int k = (tid >> 6) * 8 + u;
            float v = W0[(size_t)(kc * 64 + k) * HH + lane];
            bw[lane][k] = __float2bfloat16(v);
        }
        __syncthreads();
#pragma unroll
        for (int ks = 0; ks < 2; ++ks) {
            short8 a0 = *(const short8*)&ax[arow][ks * 32 + kq];
            short8 a1 = *(const short8*)&ax[arow + 16][ks * 32 + kq];
#pragma unroll
            for (int cf = 0; cf < 4; ++cf) {
                short8 b = *(const short8*)&bw[cf * 16 + (lane & 15)][ks * 32 + kq];
                acc[0][cf] = __builtin_amdgcn_mfma_f32_16x16x32_bf16(a0, b, acc[0][cf], 0, 0, 0);
                acc[1][cf] = __builtin_amdgcn_mfma_f32_16x16x32_bf16(a1, b, acc[1][cf], 0, 0, 0);
            }
        }
    }

#pragma unroll
    for (int nf = 0; nf < 2; ++nf) {
#pragma unroll
        for (int cf = 0; cf < 4; ++cf) {
            int c = cf * 16 + (lane & 15);
            float bias = b0[c];
#pragma unroll
            for (int r = 0; r < 4; ++r) {
                int node = nbase + w * 32 + nf * 16 + ((lane >> 4) << 2) + r;
                if (node < NN) {
                    float v = fmaxf(acc[nf][cf][r] + bias, 0.f);
                    h0f[(size_t)node * HH + c] = v;
                    h0b[(size_t)node * HH + c] = f2b(v);
                }
            }
        }
    }
}

// ---------------- layer pass 0: SpMM over src<CHS (3.2MB L2-resident), fp32 acc out ----------------
__global__ __launch_bounds__(256, 8) void k_layer_p0(
        const unsigned short* __restrict__ hin,
        const int* __restrict__ row_ptr, const int* __restrict__ row_mid,
        const unsigned* __restrict__ pay, float* __restrict__ accbuf) {
    int lane = threadIdx.x & 63;
    int half = lane >> 5;
    int j = lane & 31;
    int n0 = (blockIdx.x * 4 + (threadIdx.x >> 6)) * 4;

    const unsigned* __restrict__ hin32 = (const unsigned*)hin;

#pragma unroll
    for (int u = 0; u < 4; ++u) {
        int n = n0 + u;
        int rb = row_ptr[n], re = row_mid[n];
        float ax0 = 0.f, ay0 = 0.f, ax1 = 0.f, ay1 = 0.f;
        for (int base = rb; base < re; base += 64) {
            int idx = base + lane;
            unsigned pv = (idx < re) ? pay[idx] : 0u;
            int ecnt = min(64, re - base);
            for (int k = 0; k < ecnt; k += 8) {
                unsigned pk[8];
#pragma unroll
                for (int t = 0; t < 8; t++)
                    pk[t] = (unsigned)__builtin_amdgcn_readlane((int)pv, k + t);
                unsigned m0 = half ? pk[1] : pk[0];
                unsigned m1 = half ? pk[3] : pk[2];
                unsigned m2 = half ? pk[5] : pk[4];
                unsigned m3 = half ? pk[7] : pk[6];
                unsigned u0 = hin32[(size_t)(m0 >> 16) * 32 + j];
                unsigned u1 = hin32[(size_t)(m1 >> 16) * 32 + j];
                unsigned u2 = hin32[(size_t)(m2 >> 16) * 32 + j];
                unsigned u3 = hin32[(size_t)(m3 >> 16) * 32 + j];
                float w0 = __uint_as_float((m0 & 0xFFFFu) << 16);
                float w1 = __uint_as_float((m1 & 0xFFFFu) << 16);
                float w2 = __uint_as_float((m2 & 0xFFFFu) << 16);
                float w3 = __uint_as_float((m3 & 0xFFFFu) << 16);
                ax0 = fmaf(w0, __uint_as_float(u0 << 16), ax0);
                ay0 = fmaf(w0, __uint_as_float(u0 & 0xFFFF0000u), ay0);
                ax1 = fmaf(w1, __uint_as_float(u1 << 16), ax1);
                ay1 = fmaf(w1, __uint_as_float(u1 & 0xFFFF0000u), ay1);
                ax0 = fmaf(w2, __uint_as_float(u2 << 16), ax0);
                ay0 = fmaf(w2, __uint_as_float(u2 & 0xFFFF0000u), ay0);
                ax1 = fmaf(w3, __uint_as_float(u3 << 16), ax1);
                ay1 = fmaf(w3, __uint_as_float(u3 & 0xFFFF0000u), ay1);
            }
        }
        float ax = ax0 + ax1, ay = ay0 + ay1;
        ax += __shfl_xor(ax, 32);
        ay += __shfl_xor(ay, 32);
        float vx = __shfl(ax, lane >> 1);
        float vy = __shfl(ay, lane >> 1);
        float accv = (lane & 1) ? vy : vx;
        accbuf[(size_t)n * HH + lane] = accv;
    }
}

// ---------------- layer pass 1: SpMM over src>=CHS + acc-in + blend + matvec + relu ----------------
__global__ __launch_bounds__(256, 8) void k_layer_p1(
        const unsigned short* __restrict__ hin, const float* __restrict__ h0,
        const int* __restrict__ row_ptr, const int* __restrict__ row_mid,
        const unsigned* __restrict__ pay, const float* __restrict__ accbuf,
        const float* __restrict__ Wl, float beta,
        unsigned short* __restrict__ hout) {
    int lane = threadIdx.x & 63;
    int half = lane >> 5;
    int j = lane & 31;
    int n0 = (blockIdx.x * 4 + (threadIdx.x >> 6)) * 4;

    const unsigned* __restrict__ hin32 = (const unsigned*)hin;

    float hmix[4];
#pragma unroll
    for (int u = 0; u < 4; ++u) {
        int n = n0 + u;
        int rb = row_mid[n], re = row_ptr[n + 1];
        float ax0 = 0.f, ay0 = 0.f, ax1 = 0.f, ay1 = 0.f;
        for (int base = rb; base < re; base += 64) {
            int idx = base + lane;
            unsigned pv = (idx < re) ? pay[idx] : 0u;
            int ecnt = min(64, re - base);
            for (int k = 0; k < ecnt; k += 8) {
                unsigned pk[8];
#pragma unroll
                for (int t = 0; t < 8; t++)
                    pk[t] = (unsigned)__builtin_amdgcn_readlane((int)pv, k + t);
                unsigned m0 = half ? pk[1] : pk[0];
                unsigned m1 = half ? pk[3] : pk[2];
                unsigned m2 = half ? pk[5] : pk[4];
                unsigned m3 = half ? pk[7] : pk[6];
                unsigned u0 = hin32[(size_t)(m0 >> 16) * 32 + j];
                unsigned u1 = hin32[(size_t)(m1 >> 16) * 32 + j];
                unsigned u2 = hin32[(size_t)(m2 >> 16) * 32 + j];
                unsigned u3 = hin32[(size_t)(m3 >> 16) * 32 + j];
                float w0 = __uint_as_float((m0 & 0xFFFFu) << 16);
                float w1 = __uint_as_float((m1 & 0xFFFFu) << 16);
                float w2 = __uint_as_float((m2 & 0xFFFFu) << 16);
                float w3 = __uint_as_float((m3 & 0xFFFFu) << 16);
                ax0 = fmaf(w0, __uint_as_float(u0 << 16), ax0);
                ay0 = fmaf(w0, __uint_as_float(u0 & 0xFFFF0000u), ay0);
                ax1 = fmaf(w1, __uint_as_float(u1 << 16), ax1);
                ay1 = fmaf(w1, __uint_as_float(u1 & 0xFFFF0000u), ay1);
                ax0 = fmaf(w2, __uint_as_float(u2 << 16), ax0);
                ay0 = fmaf(w2, __uint_as_float(u2 & 0xFFFF0000u), ay0);
                ax1 = fmaf(w3, __uint_as_float(u3 << 16), ax1);
                ay1 = fmaf(w3, __uint_as_float(u3 & 0xFFFF0000u), ay1);
            }
        }
        float ax = ax0 + ax1, ay = ay0 + ay1;
        ax += __shfl_xor(ax, 32);
        ay += __shfl_xor(ay, 32);
        float vx = __shfl(ax, lane >> 1);
        float vy = __shfl(ay, lane >> 1);
        float accv = (lane & 1) ? vy : vx;
        float acc = accv + accbuf[(size_t)n * HH + lane];
        hmix[u] = fmaf(0.9f, acc, 0.1f * h0[(size_t)n * HH + lane]);
    }

    int hb[4];
#pragma unroll
    for (int u = 0; u < 4; ++u) hb[u] = __float_as_int(hmix[u]);
    float a2[4] = {0.f, 0.f, 0.f, 0.f};
#pragma unroll
    for (int jj = 0; jj < HH; jj++) {
        float wr = Wl[jj * HH + lane];
#pragma unroll
        for (int u = 0; u < 4; ++u) {
            float hj = __int_as_float(__builtin_amdgcn_readlane(hb[u], jj));
            a2[u] = fmaf(hj, wr, a2[u]);
        }
    }
#pragma unroll
    for (int u = 0; u < 4; ++u) {
        float outv = (1.f - beta) * hmix[u] + beta * a2[u];
        hout[(size_t)(n0 + u) * HH + lane] = f2b(fmaxf(outv, 0.f));
    }
}

// ---------------- head via MFMA: coarse LDS staging of W2b, 4 barriers total ----------------
__global__ __launch_bounds__(512) void k_head(const unsigned short* __restrict__ h,
                                              const unsigned short* __restrict__ W2b,
                                              const float* __restrict__ b2,
                                              float* __restrict__ out) {
    __shared__ __align__(16) unsigned short Bl[32 * 1056];  // [i][cr*66 + j]

    int tid = threadIdx.x;
    int lane = tid & 63;
    int w = tid >> 6;
    int nbase = blockIdx.x * 256;
    int ct = blockIdx.y;         // 0..2
    int c0 = ct * 16;

    int kq = (lane >> 4) * 8;
    int arow = w * 32 + (lane & 15);
    int rb4 = w * 32 + ((lane >> 4) << 2);

    int ra0 = min(nbase + arow, NN - 1);
    int ra1 = min(nbase + arow + 16, NN - 1);
    short8 af00 = *(const short8*)&h[(size_t)ra0 * HH + kq];
    short8 af01 = *(const short8*)&h[(size_t)ra0 * HH + 32 + kq];
    short8 af10 = *(const short8*)&h[(size_t)ra1 * HH + kq];
    short8 af11 = *(const short8*)&h[(size_t)ra1 * HH + 32 + kq];

    const unsigned short* srow[8];
#pragma unroll
    for (int r = 0; r < 4; ++r) {
        srow[r]     = &h[(size_t)min(nbase + rb4 + r, NN - 1) * HH];
        srow[4 + r] = &h[(size_t)min(nbase + rb4 + 16 + r, NN - 1) * HH];
    }

    const f32x4 zf = (f32x4){0.f, 0.f, 0.f, 0.f};
    f32x4 acc0 = zf, acc1 = zf;

    const unsigned short* __restrict__ Wslice = W2b + (size_t)ct * 65536;

    for (int ph = 0; ph < 2; ++ph) {
        __syncthreads();
        const unsigned short* src = Wslice + (size_t)ph * 32768;
#pragma unroll
        for (int rnd = 0; rnd < 8; ++rnd) {
            int cid = rnd * 512 + tid;
            int il = cid >> 7;
            int rem = cid & 127;
            int cr = rem >> 3;
            int jg = rem & 7;
            *(short8*)&Bl[il * 1056 + cr * 66 + jg * 8] =
                *(const short8*)&src[(size_t)cid * 8];
        }
        __syncthreads();

#pragma unroll
        for (int ihl = 0; ihl < 8; ++ihl) {
            int ibase = ihl * 4;
            int ig = ph * 32 + ibase;
            short8 B00 = *(const short8*)&Bl[(ibase + 0) * 1056 + (lane & 15) * 66 + kq];
            short8 B01 = *(const short8*)&Bl[(ibase + 0) * 1056 + (lane & 15) * 66 + 32 + kq];
            short8 B10 = *(const short8*)&Bl[(ibase + 1) * 1056 + (lane & 15) * 66 + kq];
            short8 B11 = *(const short8*)&Bl[(ibase + 1) * 1056 + (lane & 15) * 66 + 32 + kq];
            short8 B20 = *(const short8*)&Bl[(ibase + 2) * 1056 + (lane & 15) * 66 + kq];
            short8 B21 = *(const short8*)&Bl[(ibase + 2) * 1056 + (lane & 15) * 66 + 32 + kq];
            short8 B30 = *(const short8*)&Bl[(ibase + 3) * 1056 + (lane & 15) * 66 + kq];
            short8 B31 = *(const short8*)&Bl[(ibase + 3) * 1056 + (lane & 15) * 66 + 32 + kq];
            short4v sa0 = *(const short4v*)&srow[0][ig];
            short4v sa1 = *(const short4v*)&srow[1][ig];
            short4v sa2 = *(const short4v*)&srow[2][ig];
            short4v sa3 = *(const short4v*)&srow[3][ig];
            short4v sb0 = *(const short4v*)&srow[4][ig];
            short4v sb1 = *(const short4v*)&srow[5][ig];
            short4v sb2 = *(const short4v*)&srow[6][ig];
            short4v sb3 = *(const short4v*)&srow[7][ig];

#define ILB(IL, B0, B1)                                                          \
            {                                                                    \
                f32x4 t;                                                         \
                t = __builtin_amdgcn_mfma_f32_16x16x32_bf16(af00, B0, zf, 0, 0, 0); \
                t = __builtin_amdgcn_mfma_f32_16x16x32_bf16(af01, B1, t, 0, 0, 0);  \
                acc0[0] = fmaf(b2f((unsigned short)sa0[IL]), t[0], acc0[0]);     \
                acc0[1] = fmaf(b2f((unsigned short)sa1[IL]), t[1], acc0[1]);     \
                acc0[2] = fmaf(b2f((unsigned short)sa2[IL]), t[2], acc0[2]);     \
                acc0[3] = fmaf(b2f((unsigned short)sa3[IL]), t[3], acc0[3]);     \
                t = __builtin_amdgcn_mfma_f32_16x16x32_bf16(af10, B0, zf, 0, 0, 0); \
                t = __builtin_amdgcn_mfma_f32_16x16x32_bf16(af11, B1, t, 0, 0, 0);  \
                acc1[0] = fmaf(b2f((unsigned short)sb0[IL]), t[0], acc1[0]);     \
                acc1[1] = fmaf(b2f((unsigned short)sb1[IL]), t[1], acc1[1]);     \
                acc1[2] = fmaf(b2f((unsigned short)sb2[IL]), t[2], acc1[2]);     \
                acc1[3] = fmaf(b2f((unsigned short)sb3[IL]), t[3], acc1[3]);     \
            }
            ILB(0, B00, B01)
            ILB(1, B10, B11)
            ILB(2, B20, B21)
            ILB(3, B30, B31)
#undef ILB
        }
    }

    int c = c0 + (lane & 15);
    if (c < CC) {
        float bias = b2[c];
#pragma unroll
        for (int r = 0; r < 4; ++r) {
            int node0 = nbase + rb4 + r;
            if (node0 < NN) out[(size_t)node0 * CC + c] = acc0[r] + bias;
            int node1 = nbase + rb4 + 16 + r;
            if (node1 < NN) out[(size_t)node1 * CC + c] = acc1[r] + bias;
        }
    }
}

// ---------------- log_softmax in place, wave per node ----------------
__global__ void k_lsm(float* __restrict__ out) {
    int lane = threadIdx.x & 63;
    int n = (blockIdx.x * 256 + threadIdx.x) >> 6;
    if (n >= NN) return;
    float x = (lane < CC) ? out[(size_t)n * CC + lane] : -INFINITY;
    float m = x;
    for (int off = 32; off; off >>= 1) m = fmaxf(m, __shfl_xor(m, off));
    float e = (lane < CC) ? expf(x - m) : 0.f;
    float s = e;
    for (int off = 32; off; off >>= 1) s += __shfl_xor(s, off);
    float lse = m + logf(s);
    if (lane < CC) out[(size_t)n * CC + lane] = x - lse;
}

extern "C" void kernel_launch(void* const* d_in, const int* in_sizes, int n_in,
                              void* d_out, int out_size, void* d_ws, size_t ws_size,
                              hipStream_t stream) {
    const float* x  = (const float*)d_in[0];
    const int*   ei = (const int*)d_in[1];
    const float* ew = (const float*)d_in[2];
    const float* W0 = (const float*)d_in[3];
    const float* b0 = (const float*)d_in[4];
    const float* Wl = (const float*)d_in[5];
    const float* W2 = (const float*)d_in[6];
    const float* b2 = (const float*)d_in[7];
    float* out = (float*)d_out;

    char* ws = (char*)d_ws;
    size_t off = 0;
    auto alloc = [&](size_t b) { size_t o = off; off += (b + 255) & ~(size_t)255; return o; };
    float*          h0f = (float*)(ws + alloc((size_t)NN * HH * 4));
    unsigned short* h0b = (unsigned short*)(ws + alloc((size_t)NN * HH * 2));
    unsigned short* hA  = (unsigned short*)(ws + alloc((size_t)NN * HH * 2));
    unsigned short* hB  = (unsigned short*)(ws + alloc((size_t)NN * HH * 2));
    float*    accbuf  = (float*)(ws + alloc((size_t)NN * HH * 4));
    int*      bcnt    = (int*)(ws + alloc((size_t)NB * 4));
    int*      bbase   = (int*)(ws + alloc((size_t)(NB + 1) * 4));
    int*      bcur    = (int*)(ws + alloc((size_t)NB * 4));
    int*      row_ptr = (int*)(ws + alloc((size_t)(NN + 1) * 4));
    int*      row_mid = (int*)(ws + alloc((size_t)NN * 4));
    uint2*    ebuk    = (uint2*)(ws + alloc((size_t)EE * 8));
    unsigned* pay     = (unsigned*)(ws + alloc((size_t)EE * 4));
    unsigned short* W2b = (unsigned short*)(ws + alloc((size_t)3 * 64 * 16 * 64 * 2));

    const int* srcp = ei;
    const int* dstp = ei + EE;

    hipMemsetAsync(bcnt, 0, (size_t)NB * 4, stream);
    k_bhist<<<NPART, 256, 0, stream>>>(dstp, bcnt);
    k_bscan<<<1, 1024, 0, stream>>>(bcnt, bbase);
    k_binit<<<(NB + 255) / 256, 256, 0, stream>>>(bbase, bcur);
    k_part<<<NPART, 256, 0, stream>>>(srcp, dstp, ew, bcur, ebuk);
    k_sub<<<NB, 256, 0, stream>>>(bbase, ebuk, pay, row_ptr, row_mid);
    k_w2b<<<768, 256, 0, stream>>>(W2, W2b);

    k_h0m<<<196, 512, 0, stream>>>(x, W0, b0, h0f, h0b);

    const unsigned short* hin = h0b;
    unsigned short* ho = hA;
    for (int l = 0; l < LL; l++) {
        float beta = (float)log(0.5 / (double)(l + 1) + 1.0);
        k_layer_p0<<<3125, 256, 0, stream>>>(hin, row_ptr, row_mid, pay, accbuf);
        k_layer_p1<<<3125, 256, 0, stream>>>(hin, h0f, row_ptr, row_mid, pay, accbuf,
                                             Wl + (size_t)l * HH * HH, beta, ho);
        hin = ho;
        ho = (ho == hA) ? hB : hA;
    }

    k_head<<<dim3(196, 3), 512, 0, stream>>>(hin, W2b, b2, out);
    k_lsm<<<(NN * 64 + 255) / 256, 256, 0, stream>>>(out);
}

// Round 22
// 467.509 us; speedup vs baseline: 1.2893x; 1.1909x over previous
//
#include <hip/hip_runtime.h>
#include <hip/hip_bf16.h>
#include <math.h>

#define NN 50000
#define FF 256
#define HH 64
#define LL 8
#define EE 1600000
#define CC 40

#define BK 64                       // dst nodes per bucket
#define NB ((NN + BK - 1) / BK)     // 782 buckets
#define PBK 4096                    // edges per partition block
#define NPART ((EE + PBK - 1) / PBK)

using short8 = __attribute__((ext_vector_type(8))) short;
using short4v = __attribute__((ext_vector_type(4))) short;
using f32x4  = __attribute__((ext_vector_type(4))) float;

static __device__ __forceinline__ unsigned short f2b(float f) {
    union { __hip_bfloat16 h; unsigned short u; } cv;
    cv.h = __float2bfloat16(f);
    return cv.u;
}
static __device__ __forceinline__ float b2f(unsigned short u) {
    return __uint_as_float((unsigned)u << 16);
}

// ---------------- bucket-level histogram (LDS-aggregated) ----------------
__global__ void k_bhist(const int* __restrict__ dst, int* __restrict__ bcnt) {
    __shared__ int lh[NB];
    int t = threadIdx.x;
    int e0 = blockIdx.x * PBK;
    int e1 = min(e0 + PBK, EE);
    for (int i = t; i < NB; i += 256) lh[i] = 0;
    __syncthreads();
    for (int e = e0 + t; e < e1; e += 256)
        atomicAdd(&lh[(unsigned)dst[e] >> 6], 1);
    __syncthreads();
    for (int i = t; i < NB; i += 256)
        if (lh[i]) atomicAdd(&bcnt[i], lh[i]);
}

// exclusive scan of NB bucket counts (one 1024-thread block)
__global__ void k_bscan(const int* __restrict__ bcnt, int* __restrict__ bbase) {
    __shared__ int buf[1024];
    int t = threadIdx.x;
    int v = (t < NB) ? bcnt[t] : 0;
    int vin = v;
    buf[t] = v;
    __syncthreads();
    for (int off = 1; off < 1024; off <<= 1) {
        int u = (t >= off) ? buf[t - off] : 0;
        __syncthreads();
        buf[t] += u;
        __syncthreads();
    }
    if (t < NB) bbase[t] = buf[t] - vin;  // exclusive
    if (t == 0) bbase[NB] = EE;
}

__global__ void k_binit(const int* __restrict__ bbase, int* __restrict__ bcur) {
    int t = blockIdx.x * 256 + threadIdx.x;
    if (t < NB) bcur[t] = bbase[t];
}

// ---------------- pass 1: bucket partition (dst>>6), LDS-aggregated runs ----------------
__global__ void k_part(const int* __restrict__ src, const int* __restrict__ dst,
                       const float* __restrict__ w, int* __restrict__ bcur,
                       uint2* __restrict__ ebuk) {
    __shared__ int lh[NB];
    __shared__ int lbase[NB];
    int t = threadIdx.x;
    int e0 = blockIdx.x * PBK;
    int e1 = min(e0 + PBK, EE);
    for (int i = t; i < NB; i += 256) lh[i] = 0;
    __syncthreads();
    for (int e = e0 + t; e < e1; e += 256)
        atomicAdd(&lh[(unsigned)dst[e] >> 6], 1);
    __syncthreads();
    for (int i = t; i < NB; i += 256) {
        int c = lh[i];
        lbase[i] = c ? atomicAdd(&bcur[i], c) : 0;
    }
    __syncthreads();
    for (int i = t; i < NB; i += 256) lh[i] = 0;
    __syncthreads();
    for (int e = e0 + t; e < e1; e += 256) {
        int d = dst[e];
        int b = (unsigned)d >> 6;
        int r = atomicAdd(&lh[b], 1);
        ebuk[lbase[b] + r] = make_uint2(((unsigned)src[e] << 16) | (unsigned)f2b(w[e]),
                                        (unsigned)d);
    }
}

// ---------------- pass 2: per-bucket count + scan + row_ptr + local scatter ----------------
__global__ void k_sub(const int* __restrict__ bbase, const uint2* __restrict__ ebuk,
                      unsigned* __restrict__ pay, int* __restrict__ row_ptr) {
    __shared__ int lcnt[BK];
    __shared__ int lcur[BK];
    int b = blockIdx.x;
    int d0 = b * BK;
    int bksz = min(BK, NN - d0);
    int t = threadIdx.x;
    if (t < BK) lcnt[t] = 0;
    __syncthreads();
    int lo = bbase[b], hi = bbase[b + 1];
    for (int i = lo + t; i < hi; i += 256)
        atomicAdd(&lcnt[ebuk[i].y - d0], 1);
    __syncthreads();
    if (t < 64) {
        int vin = lcnt[t];
        int v = vin;
        for (int off = 1; off < 64; off <<= 1) {
            int u = __shfl_up(v, off);
            if (t >= off) v += u;
        }
        int excl = v - vin + lo;
        lcur[t] = excl;
        if (t < bksz) row_ptr[d0 + t] = excl;
    }
    if (b == NB - 1 && t == 0) row_ptr[NN] = EE;
    __syncthreads();
    for (int i = lo + t; i < hi; i += 256) {
        uint2 pk = ebuk[i];
        int p = atomicAdd(&lcur[pk.y - d0], 1);
        pay[p] = pk.x;
    }
}

// ---------------- W2 -> bf16, layout [ct][i][cr][j] ----------------
__global__ void k_w2b(const float* __restrict__ W2, unsigned short* __restrict__ W2b) {
    int o = blockIdx.x * 256 + threadIdx.x;
    if (o < 3 * 64 * 16 * 64) {
        int j = o & 63;
        int cr = (o >> 6) & 15;
        int i = (o >> 10) & 63;
        int ct = o >> 16;
        int c = ct * 16 + cr;
        float v = (c < CC) ? W2[((size_t)i * 64 + j) * CC + c] : 0.f;
        W2b[o] = f2b(v);
    }
}

// ---------------- initial projection via MFMA: h0 = relu(x @ W0 + b0) ----------------
__global__ __launch_bounds__(512) void k_h0m(const float* __restrict__ x,
                                             const float* __restrict__ W0,
                                             const float* __restrict__ b0,
                                             float* __restrict__ h0f,
                                             unsigned short* __restrict__ h0b) {
    __shared__ __align__(16) __hip_bfloat16 ax[256][72];
    __shared__ __align__(16) __hip_bfloat16 bw[64][72];

    int tid = threadIdx.x;
    int lane = tid & 63;
    int w = tid >> 6;
    int nbase = blockIdx.x * 256;

    f32x4 acc[2][4];
#pragma unroll
    for (int nf = 0; nf < 2; ++nf)
#pragma unroll
        for (int cf = 0; cf < 4; ++cf) acc[nf][cf] = (f32x4){0.f, 0.f, 0.f, 0.f};

    int arow = w * 32 + (lane & 15);
    int kq = (lane >> 4) * 8;

    for (int kc = 0; kc < 4; ++kc) {
        __syncthreads();
#pragma unroll
        for (int p = 0; p < 8; ++p) {
            int q = p * 512 + tid;
            int r = q >> 4, cq = q & 15;
            int node = nbase + r;
            float4 v = {0.f, 0.f, 0.f, 0.f};
            if (node < NN) v = *(const float4*)&x[(size_t)node * FF + kc * 64 + cq * 4];
            __hip_bfloat16* d = &ax[r][cq * 4];
            d[0] = __float2bfloat16(v.x);
            d[1] = __float2bfloat16(v.y);
            d[2] = __float2bfloat16(v.z);
            d[3] = __float2bfloat16(v.w);
        }
#pragma unroll
        for (int u = 0; u < 8; ++u) {
            int k = (tid >> 6) * 8 + u;
            float v = W0[(size_t)(kc * 64 + k) * HH + lane];
            bw[lane][k] = __float2bfloat16(v);
        }
        __syncthreads();
#pragma unroll
        for (int ks = 0; ks < 2; ++ks) {
            short8 a0 = *(const short8*)&ax[arow][ks * 32 + kq];
            short8 a1 = *(const short8*)&ax[arow + 16][ks * 32 + kq];
#pragma unroll
            for (int cf = 0; cf < 4; ++cf) {
                short8 b = *(const short8*)&bw[cf * 16 + (lane & 15)][ks * 32 + kq];
                acc[0][cf] = __builtin_amdgcn_mfma_f32_16x16x32_bf16(a0, b, acc[0][cf], 0, 0, 0);
                acc[1][cf] = __builtin_amdgcn_mfma_f32_16x16x32_bf16(a1, b, acc[1][cf], 0, 0, 0);
            }
        }
    }

#pragma unroll
    for (int nf = 0; nf < 2; ++nf) {
#pragma unroll
        for (int cf = 0; cf < 4; ++cf) {
            int c = cf * 16 + (lane & 15);
            float bias = b0[c];
#pragma unroll
            for (int r = 0; r < 4; ++r) {
                int node = nbase + w * 32 + nf * 16 + ((lane >> 4) << 2) + r;
                if (node < NN) {
                    float v = fmaxf(acc[nf][cf][r] + bias, 0.f);
                    h0f[(size_t)node * HH + c] = v;
                    h0b[(size_t)node * HH + c] = f2b(v);
                }
            }
        }
    }
}

// ---------------- fused layer: paired-edge bf16x2 SpMM + blend + matvec + relu ----------------
__global__ __launch_bounds__(256, 8) void k_layer(
        const unsigned short* __restrict__ hin, const float* __restrict__ h0,
        const int* __restrict__ row_ptr, const unsigned* __restrict__ pay,
        const float* __restrict__ Wl, float beta,
        unsigned short* __restrict__ hout) {
    int lane = threadIdx.x & 63;
    int half = lane >> 5;
    int j = lane & 31;                 // channel pair (2j, 2j+1)
    int n0 = (blockIdx.x * 4 + (threadIdx.x >> 6)) * 4;

    const unsigned* __restrict__ hin32 = (const unsigned*)hin;

    float hmix[4];
#pragma unroll
    for (int u = 0; u < 4; ++u) {
        int n = n0 + u;
        int rb = row_ptr[n], re = row_ptr[n + 1];
        float ax0 = 0.f, ay0 = 0.f, ax1 = 0.f, ay1 = 0.f;
        for (int base = rb; base < re; base += 64) {
            int idx = base + lane;
            unsigned pv = (idx < re) ? pay[idx] : 0u;  // pad: src=0, w=+0
            int ecnt = min(64, re - base);
            for (int k = 0; k < ecnt; k += 8) {
                unsigned pk[8];
#pragma unroll
                for (int t = 0; t < 8; t++)
                    pk[t] = (unsigned)__builtin_amdgcn_readlane((int)pv, k + t);
                unsigned m0 = half ? pk[1] : pk[0];
                unsigned m1 = half ? pk[3] : pk[2];
                unsigned m2 = half ? pk[5] : pk[4];
                unsigned m3 = half ? pk[7] : pk[6];
                unsigned u0 = hin32[(size_t)(m0 >> 16) * 32 + j];
                unsigned u1 = hin32[(size_t)(m1 >> 16) * 32 + j];
                unsigned u2 = hin32[(size_t)(m2 >> 16) * 32 + j];
                unsigned u3 = hin32[(size_t)(m3 >> 16) * 32 + j];
                float w0 = __uint_as_float((m0 & 0xFFFFu) << 16);
                float w1 = __uint_as_float((m1 & 0xFFFFu) << 16);
                float w2 = __uint_as_float((m2 & 0xFFFFu) << 16);
                float w3 = __uint_as_float((m3 & 0xFFFFu) << 16);
                ax0 = fmaf(w0, __uint_as_float(u0 << 16), ax0);
                ay0 = fmaf(w0, __uint_as_float(u0 & 0xFFFF0000u), ay0);
                ax1 = fmaf(w1, __uint_as_float(u1 << 16), ax1);
                ay1 = fmaf(w1, __uint_as_float(u1 & 0xFFFF0000u), ay1);
                ax0 = fmaf(w2, __uint_as_float(u2 << 16), ax0);
                ay0 = fmaf(w2, __uint_as_float(u2 & 0xFFFF0000u), ay0);
                ax1 = fmaf(w3, __uint_as_float(u3 << 16), ax1);
                ay1 = fmaf(w3, __uint_as_float(u3 & 0xFFFF0000u), ay1);
            }
        }
        float ax = ax0 + ax1, ay = ay0 + ay1;
        ax += __shfl_xor(ax, 32);       // combine even/odd halves
        ay += __shfl_xor(ay, 32);
        float vx = __shfl(ax, lane >> 1);
        float vy = __shfl(ay, lane >> 1);
        float acc = (lane & 1) ? vy : vx;
        hmix[u] = fmaf(0.9f, acc, 0.1f * h0[(size_t)n * HH + lane]);
    }

    int hb[4];
#pragma unroll
    for (int u = 0; u < 4; ++u) hb[u] = __float_as_int(hmix[u]);
    float a2[4] = {0.f, 0.f, 0.f, 0.f};
#pragma unroll
    for (int jj = 0; jj < HH; jj++) {
        float wr = Wl[jj * HH + lane];
#pragma unroll
        for (int u = 0; u < 4; ++u) {
            float hj = __int_as_float(__builtin_amdgcn_readlane(hb[u], jj));
            a2[u] = fmaf(hj, wr, a2[u]);
        }
    }
#pragma unroll
    for (int u = 0; u < 4; ++u) {
        float outv = (1.f - beta) * hmix[u] + beta * a2[u];
        hout[(size_t)(n0 + u) * HH + lane] = f2b(fmaxf(outv, 0.f));
    }
}

// ---------------- head via MFMA: coarse LDS staging (stride 72: bank-conflict-free) ----------------
__global__ __launch_bounds__(512) void k_head(const unsigned short* __restrict__ h,
                                              const unsigned short* __restrict__ W2b,
                                              const float* __restrict__ b2,
                                              float* __restrict__ out) {
    __shared__ __align__(16) unsigned short Bl[32 * 1152];  // [i][cr*72 + j]

    int tid = threadIdx.x;
    int lane = tid & 63;
    int w = tid >> 6;
    int nbase = blockIdx.x * 256;
    int ct = blockIdx.y;         // 0..2
    int c0 = ct * 16;

    int kq = (lane >> 4) * 8;
    int arow = w * 32 + (lane & 15);
    int rb4 = w * 32 + ((lane >> 4) << 2);

    int ra0 = min(nbase + arow, NN - 1);
    int ra1 = min(nbase + arow + 16, NN - 1);
    short8 af00 = *(const short8*)&h[(size_t)ra0 * HH + kq];
    short8 af01 = *(const short8*)&h[(size_t)ra0 * HH + 32 + kq];
    short8 af10 = *(const short8*)&h[(size_t)ra1 * HH + kq];
    short8 af11 = *(const short8*)&h[(size_t)ra1 * HH + 32 + kq];

    const unsigned short* srow[8];
#pragma unroll
    for (int r = 0; r < 4; ++r) {
        srow[r]     = &h[(size_t)min(nbase + rb4 + r, NN - 1) * HH];
        srow[4 + r] = &h[(size_t)min(nbase + rb4 + 16 + r, NN - 1) * HH];
    }

    const f32x4 zf = (f32x4){0.f, 0.f, 0.f, 0.f};
    f32x4 acc0 = zf, acc1 = zf;

    const unsigned short* __restrict__ Wslice = W2b + (size_t)ct * 65536;

    for (int ph = 0; ph < 2; ++ph) {
        __syncthreads();
        const unsigned short* src = Wslice + (size_t)ph * 32768;
#pragma unroll
        for (int rnd = 0; rnd < 8; ++rnd) {
            int cid = rnd * 512 + tid;
            int il = cid >> 7;
            int rem = cid & 127;
            int cr = rem >> 3;
            int jg = rem & 7;
            *(short8*)&Bl[il * 1152 + cr * 72 + jg * 8] =
                *(const short8*)&src[(size_t)cid * 8];
        }
        __syncthreads();

#pragma unroll
        for (int ihl = 0; ihl < 8; ++ihl) {
            int ibase = ihl * 4;
            int ig = ph * 32 + ibase;
            short8 B00 = *(const short8*)&Bl[(ibase + 0) * 1152 + (lane & 15) * 72 + kq];
            short8 B01 = *(const short8*)&Bl[(ibase + 0) * 1152 + (lane & 15) * 72 + 32 + kq];
            short8 B10 = *(const short8*)&Bl[(ibase + 1) * 1152 + (lane & 15) * 72 + kq];
            short8 B11 = *(const short8*)&Bl[(ibase + 1) * 1152 + (lane & 15) * 72 + 32 + kq];
            short8 B20 = *(const short8*)&Bl[(ibase + 2) * 1152 + (lane & 15) * 72 + kq];
            short8 B21 = *(const short8*)&Bl[(ibase + 2) * 1152 + (lane & 15) * 72 + 32 + kq];
            short8 B30 = *(const short8*)&Bl[(ibase + 3) * 1152 + (lane & 15) * 72 + kq];
            short8 B31 = *(const short8*)&Bl[(ibase + 3) * 1152 + (lane & 15) * 72 + 32 + kq];
            short4v sa0 = *(const short4v*)&srow[0][ig];
            short4v sa1 = *(const short4v*)&srow[1][ig];
            short4v sa2 = *(const short4v*)&srow[2][ig];
            short4v sa3 = *(const short4v*)&srow[3][ig];
            short4v sb0 = *(const short4v*)&srow[4][ig];
            short4v sb1 = *(const short4v*)&srow[5][ig];
            short4v sb2 = *(const short4v*)&srow[6][ig];
            short4v sb3 = *(const short4v*)&srow[7][ig];

#define ILB(IL, B0, B1)                                                          \
            {                                                                    \
                f32x4 t;                                                         \
                t = __builtin_amdgcn_mfma_f32_16x16x32_bf16(af00, B0, zf, 0, 0, 0); \
                t = __builtin_amdgcn_mfma_f32_16x16x32_bf16(af01, B1, t, 0, 0, 0);  \
                acc0[0] = fmaf(b2f((unsigned short)sa0[IL]), t[0], acc0[0]);     \
                acc0[1] = fmaf(b2f((unsigned short)sa1[IL]), t[1], acc0[1]);     \
                acc0[2] = fmaf(b2f((unsigned short)sa2[IL]), t[2], acc0[2]);     \
                acc0[3] = fmaf(b2f((unsigned short)sa3[IL]), t[3], acc0[3]);     \
                t = __builtin_amdgcn_mfma_f32_16x16x32_bf16(af10, B0, zf, 0, 0, 0); \
                t = __builtin_amdgcn_mfma_f32_16x16x32_bf16(af11, B1, t, 0, 0, 0);  \
                acc1[0] = fmaf(b2f((unsigned short)sb0[IL]), t[0], acc1[0]);     \
                acc1[1] = fmaf(b2f((unsigned short)sb1[IL]), t[1], acc1[1]);     \
                acc1[2] = fmaf(b2f((unsigned short)sb2[IL]), t[2], acc1[2]);     \
                acc1[3] = fmaf(b2f((unsigned short)sb3[IL]), t[3], acc1[3]);     \
            }
            ILB(0, B00, B01)
            ILB(1, B10, B11)
            ILB(2, B20, B21)
            ILB(3, B30, B31)
#undef ILB
        }
    }

    int c = c0 + (lane & 15);
    if (c < CC) {
        float bias = b2[c];
#pragma unroll
        for (int r = 0; r < 4; ++r) {
            int node0 = nbase + rb4 + r;
            if (node0 < NN) out[(size_t)node0 * CC + c] = acc0[r] + bias;
            int node1 = nbase + rb4 + 16 + r;
            if (node1 < NN) out[(size_t)node1 * CC + c] = acc1[r] + bias;
        }
    }
}

// ---------------- log_softmax in place, wave per node ----------------
__global__ void k_lsm(float* __restrict__ out) {
    int lane = threadIdx.x & 63;
    int n = (blockIdx.x * 256 + threadIdx.x) >> 6;
    if (n >= NN) return;
    float x = (lane < CC) ? out[(size_t)n * CC + lane] : -INFINITY;
    float m = x;
    for (int off = 32; off; off >>= 1) m = fmaxf(m, __shfl_xor(m, off));
    float e = (lane < CC) ? expf(x - m) : 0.f;
    float s = e;
    for (int off = 32; off; off >>= 1) s += __shfl_xor(s, off);
    float lse = m + logf(s);
    if (lane < CC) out[(size_t)n * CC + lane] = x - lse;
}

extern "C" void kernel_launch(void* const* d_in, const int* in_sizes, int n_in,
                              void* d_out, int out_size, void* d_ws, size_t ws_size,
                              hipStream_t stream) {
    const float* x  = (const float*)d_in[0];
    const int*   ei = (const int*)d_in[1];
    const float* ew = (const float*)d_in[2];
    const float* W0 = (const float*)d_in[3];
    const float* b0 = (const float*)d_in[4];
    const float* Wl = (const float*)d_in[5];
    const float* W2 = (const float*)d_in[6];
    const float* b2 = (const float*)d_in[7];
    float* out = (float*)d_out;

    char* ws = (char*)d_ws;
    size_t off = 0;
    auto alloc = [&](size_t b) { size_t o = off; off += (b + 255) & ~(size_t)255; return o; };
    float*          h0f = (float*)(ws + alloc((size_t)NN * HH * 4));
    unsigned short* h0b = (unsigned short*)(ws + alloc((size_t)NN * HH * 2));
    unsigned short* hA  = (unsigned short*)(ws + alloc((size_t)NN * HH * 2));
    unsigned short* hB  = (unsigned short*)(ws + alloc((size_t)NN * HH * 2));
    int*      bcnt    = (int*)(ws + alloc((size_t)NB * 4));
    int*      bbase   = (int*)(ws + alloc((size_t)(NB + 1) * 4));
    int*      bcur    = (int*)(ws + alloc((size_t)NB * 4));
    int*      row_ptr = (int*)(ws + alloc((size_t)(NN + 1) * 4));
    uint2*    ebuk    = (uint2*)(ws + alloc((size_t)EE * 8));
    unsigned* pay     = (unsigned*)(ws + alloc((size_t)EE * 4));
    unsigned short* W2b = (unsigned short*)(ws + alloc((size_t)3 * 64 * 16 * 64 * 2));

    const int* srcp = ei;
    const int* dstp = ei + EE;

    hipMemsetAsync(bcnt, 0, (size_t)NB * 4, stream);
    k_bhist<<<NPART, 256, 0, stream>>>(dstp, bcnt);
    k_bscan<<<1, 1024, 0, stream>>>(bcnt, bbase);
    k_binit<<<(NB + 255) / 256, 256, 0, stream>>>(bbase, bcur);
    k_part<<<NPART, 256, 0, stream>>>(srcp, dstp, ew, bcur, ebuk);
    k_sub<<<NB, 256, 0, stream>>>(bbase, ebuk, pay, row_ptr);
    k_w2b<<<768, 256, 0, stream>>>(W2, W2b);

    k_h0m<<<196, 512, 0, stream>>>(x, W0, b0, h0f, h0b);

    const unsigned short* hin = h0b;
    unsigned short* ho = hA;
    for (int l = 0; l < LL; l++) {
        float beta = (float)log(0.5 / (double)(l + 1) + 1.0);
        k_layer<<<3125, 256, 0, stream>>>(hin, h0f, row_ptr, pay,
                                          Wl + (size_t)l * HH * HH, beta, ho);
        hin = ho;
        ho = (ho == hA) ? hB : hA;
    }

    k_head<<<dim3(196, 3), 512, 0, stream>>>(hin, W2b, b2, out);
    k_lsm<<<(NN * 64 + 255) / 256, 256, 0, stream>>>(out);
}